// Round 9
// baseline (9996.890 us; speedup 1.0000x reference)
//
#include <hip/hip_runtime.h>
#include <hip/hip_bf16.h>
#include <hip/hip_cooperative_groups.h>

namespace cg = cooperative_groups;

#define DEPTH 24
#define DM 192
#define DI 384
#define DS 16
#define DR 12
#define LSEQ 401
#define BATCH 4
#define NTOK (BATCH*LSEQ)          // 1604
#define NCLS 22
#define NC 16                      // scan time-chunks
#define TCH 26                     // ceil(401/16); last chunk = 11

#define NT1 (24*51)                // xz tiles           = 1224
#define NT2 (4*101)                // xproj tiles        = 404
#define NT3 (24*(NC-1)*8)          // scan_part tiles    = 2880
#define NT4 (24*NC*8)              // scan_fix tiles     = 3072
#define NT5 (6*51*2)               // outproj tiles      = 612

__device__ __forceinline__ float silu_f(float x) { return x / (1.f + __expf(-x)); }

struct MegaArgs {
    const float *x, *pe_w, *pe_b, *cls, *pos, *norm_w, *ipw, *cw, *cb,
                *xpw, *dtw, *dtb, *A_log, *A_b_log, *Dp, *opw, *norm_f,
                *head_w, *head_b;
    float *resA, *resB, *hidden, *xz, *dbl, *yraw, *hloc, *Pc;
    void* out;
    const unsigned short* probe;
};

// ---------- patch embed + cls + pos (4 tokens/tile); needs 1024 floats LDS ----------
__device__ void patch_tile(const MegaArgs& a, int tile, int tid, float* sm)
{
    float* xp = sm;                       // 4*256
    int g0 = tile * 4;
    #pragma unroll
    for (int j = 0; j < 4; j++) {
        int g = g0 + j;
        int b = g / LSEQ, t = g % LSEQ;
        if (t != 0) {
            int p = t - 1, pi = p / 200, pj = p % 200;
            int pp = tid >> 4, qq = tid & 15;
            xp[j * 256 + tid] = a.x[((size_t)(b * 32 + pi * 16 + pp)) * 3200 + pj * 16 + qq];
        }
    }
    __syncthreads();
    int c = tid;
    if (c < DM) {
        float acc[4] = {0.f, 0.f, 0.f, 0.f};
        for (int k = 0; k < 256; k++) {
            float w = a.pe_w[c * 256 + k];
            #pragma unroll
            for (int j = 0; j < 4; j++) acc[j] += xp[j * 256 + k] * w;
        }
        #pragma unroll
        for (int j = 0; j < 4; j++) {
            int g = g0 + j;
            int t = g % LSEQ;
            float v = (t == 0) ? a.cls[c] : (acc[j] + a.pe_b[c]);
            v += a.pos[t * DM + c];
            a.resA[(size_t)g * DM + c] = v;
            a.hidden[(size_t)g * DM + c] = v;
        }
    }
    __syncthreads();
}

// ---------- P1: fused prenorm + xz GEMM (32x32 tile, 2-stage K); 6528 floats LDS ----------
__device__ void xz_tile(const MegaArgs& a, int l, int tile, int tid, float* sm)
{
    const float* rin = (l & 1) ? a.resB : a.resA;
    float* rout      = (l & 1) ? a.resA : a.resB;
    const float* nw    = a.norm_w + (size_t)l * DM;
    const float* ipw_l = a.ipw + (size_t)l * 2 * DI * DM;
    float* As = sm;                       // 96 x 34
    float* Ws = sm + 3264;
    int bn = (tile % 24) * 32;
    int bm = (tile / 24) * 32;
    int row8 = tid >> 3, seg = tid & 7, k0 = seg * 24;
    int m = bm + row8;
    float r[24];
    float s = 0.f;
    if (m < NTOK) {
        const float* rp = rin + (size_t)m * DM + k0;
        const float* hp = a.hidden + (size_t)m * DM + k0;
        #pragma unroll
        for (int i = 0; i < 24; i++) { r[i] = rp[i] + hp[i]; s += r[i] * r[i]; }
    } else {
        #pragma unroll
        for (int i = 0; i < 24; i++) r[i] = 0.f;
    }
    s += __shfl_down(s, 4, 8);
    s += __shfl_down(s, 2, 8);
    s += __shfl_down(s, 1, 8);
    float tot = __shfl(s, 0, 8);
    float rms = rsqrtf(tot / (float)DM + 1e-5f);
    if (bn == 0 && m < NTOK) {
        float* ro = rout + (size_t)m * DM + k0;
        #pragma unroll
        for (int i = 0; i < 24; i++) ro[i] = r[i];
    }
    float av[24], wreg[24];
    {
        const float* wp = ipw_l + (size_t)(bn + row8) * DM + k0;
        #pragma unroll
        for (int i = 0; i < 24; i++) {
            av[i] = r[i] * rms * nw[k0 + i];
            wreg[i] = wp[i];
        }
    }
    int r0 = (tid >> 4) * 2, c0 = (tid & 15) * 2;
    float acc[2][2] = {};
    #pragma unroll
    for (int st = 0; st < 2; st++) {
        if (st) __syncthreads();
        if ((seg >> 2) == st) {
            int kb = k0 - st * 96;
            #pragma unroll
            for (int i = 0; i < 24; i++) {
                As[(kb + i) * 34 + row8] = av[i];
                Ws[(kb + i) * 34 + row8] = wreg[i];
            }
        }
        __syncthreads();
        #pragma unroll 8
        for (int kk = 0; kk < 96; kk++) {
            float2 aa = *(const float2*)&As[kk * 34 + r0];
            float2 ww = *(const float2*)&Ws[kk * 34 + c0];
            acc[0][0] += aa.x * ww.x; acc[0][1] += aa.x * ww.y;
            acc[1][0] += aa.y * ww.x; acc[1][1] += aa.y * ww.y;
        }
    }
    #pragma unroll
    for (int i = 0; i < 2; i++) {
        int mm = bm + r0 + i;
        if (mm >= NTOK) continue;
        #pragma unroll
        for (int j = 0; j < 2; j++)
            a.xz[(size_t)mm * (2 * DI) + bn + c0 + j] = acc[i][j];
    }
    __syncthreads();
}

// ---------- P2: xproj with conv fused (split-K=4, atomics into dbl); 7776 floats LDS ----------
__device__ void xproj_tile(const MegaArgs& a, int l, int tile, int tid, float* sm)
{
    const float* cw_l  = a.cw + (size_t)l * DI * 4;
    const float* cb_l  = a.cb + (size_t)l * DI;
    const float* xpw_l = a.xpw + (size_t)l * 44 * DI;
    float* As = sm;                       // 96 x 33
    float* Ws = sm + 3168;                // 96 x 48
    int kbase = (tile % 4) * 96;
    int bm = (tile / 4) * 32;
    for (int idx = tid; idx < 96 * 32; idx += 256) {
        int k = idx >> 5, row = idx & 31;
        int m = bm + row;
        float v = 0.f;
        if (m < 2 * NTOK) {
            int dir = m / NTOK;
            int r = m - dir * NTOK;
            int b = r / LSEQ, t = r % LSEQ;
            int ch = kbase + k;
            float acc = cb_l[ch];
            #pragma unroll
            for (int j = 0; j < 4; j++) {
                int tt = t - 3 + j;
                if (tt >= 0) {
                    int st = dir ? (LSEQ - 1 - tt) : tt;
                    acc += cw_l[ch * 4 + j] * a.xz[((size_t)(b * LSEQ + st)) * (2 * DI) + ch];
                }
            }
            v = silu_f(acc);
        }
        As[k * 33 + row] = v;
    }
    for (int i = tid; i < 96 * 48; i += 256) {
        int k = i / 48, rr = i % 48;
        Ws[k * 48 + rr] = (rr < 44) ? xpw_l[(size_t)rr * DI + kbase + k] : 0.f;
    }
    __syncthreads();
    int row = tid & 31, cg_ = tid >> 5;
    int cbase = cg_ * 6;
    float acc[6] = {};
    #pragma unroll 4
    for (int kk = 0; kk < 96; kk++) {
        float av = As[kk * 33 + row];
        #pragma unroll
        for (int j = 0; j < 6; j++) acc[j] += av * Ws[kk * 48 + cbase + j];
    }
    int m = bm + row;
    if (m < 2 * NTOK) {
        #pragma unroll
        for (int j = 0; j < 6; j++) {
            int cc = cbase + j;
            if (cc < 44) atomicAdd(&a.dbl[(size_t)m * 44 + cc], acc[j]);
        }
    }
    __syncthreads();
}

// ---------- shared scan staging: dbl slab, conv+silu xx, dt ----------
__device__ void scan_stage(const MegaArgs& a, int l,
                           int d0, int t0, int db, int dir, int b, bool guard,
                           int tid, float* sdbl, float* sdt, float* sxx,
                           float* sw, float* sb2)
{
    const float* cw_l  = a.cw + (size_t)l * DI * 4;
    const float* cb_l  = a.cb + (size_t)l * DI;
    const float* dtw_l = a.dtw + (size_t)l * DI * DR;
    const float* dtb_l = a.dtb + (size_t)l * DI;
    size_t dof44 = (size_t)db * LSEQ * 44;
    for (int i = tid; i < TCH * 44; i += 256) {
        int t = i / 44, cc = i - t * 44;
        bool v = !guard || (t0 + t) < LSEQ;
        sdbl[t * 44 + cc] = v ? a.dbl[dof44 + (size_t)(t0 + t) * 44 + cc] : 0.f;
    }
    if (tid < 192) { int d = tid / 12, r = tid - d * 12; sw[d * 12 + r] = dtw_l[(size_t)(d0 + d) * 12 + r]; }
    if (tid < 16) sb2[tid] = dtb_l[d0 + tid];
    for (int i = tid; i < TCH * 16; i += 256) {
        int t = i >> 4, d = i & 15;
        int tq = t0 + t, ch = d0 + d;
        float v = 0.f;
        if (!guard || tq < LSEQ) {
            float acc = cb_l[ch];
            #pragma unroll
            for (int j = 0; j < 4; j++) {
                int tt = tq - 3 + j;
                if (tt >= 0) {
                    int st = dir ? (LSEQ - 1 - tt) : tt;
                    acc += cw_l[ch * 4 + j] * a.xz[((size_t)(b * LSEQ + st)) * (2 * DI) + ch];
                }
            }
            v = silu_f(acc);
        }
        sxx[t * 16 + d] = v;
    }
    __syncthreads();
    for (int i = tid; i < TCH * 16; i += 256) {
        int t = i >> 4, d = i & 15;
        float a2 = sb2[d];
        #pragma unroll
        for (int r = 0; r < 12; r++) a2 += sdbl[t * 44 + r] * sw[d * 12 + r];
        sdt[t * 16 + d] = (a2 > 15.f) ? a2 : __logf(1.f + __expf(a2));
    }
    __syncthreads();
}

// ---------- P3: scan pass 1; 2184 floats LDS ----------
__device__ void scan_part_tile(const MegaArgs& a, int l, int tile, int tid, float* sm)
{
    float* sdbl = sm;            // 26*44
    float* sdt  = sm + 1144;
    float* sxx  = sm + 1560;
    float* sw   = sm + 1976;
    float* sb2  = sm + 2168;
    int dblk = tile % 24;
    int rr = tile / 24;
    int chunk = rr % (NC - 1);
    int db = rr / (NC - 1);
    int dir = db >> 2, b = db & 3;
    int d0 = dblk * 16;
    int t0 = chunk * TCH;
    scan_stage(a, l, d0, t0, db, dir, b, false, tid, sdbl, sdt, sxx, sw, sb2);
    int wave = tid >> 6, lane = tid & 63;
    int dsub = wave * 4 + (lane >> 4);
    int n = lane & 15;
    const float* Al = (dir ? a.A_b_log : a.A_log) + (size_t)l * DI * DS;
    float Aval = -__expf(Al[(d0 + dsub) * DS + n]);
    float h = 0.f, P = 1.f;
    #pragma unroll
    for (int i = 0; i < TCH; i++) {
        float dtv = sdt[i * 16 + dsub];
        float xv  = sxx[i * 16 + dsub];
        float Bv  = sdbl[i * 44 + 12 + n];
        float dA = __expf(dtv * Aval);
        h = dA * h + (dtv * xv) * Bv;
        P *= dA;
    }
    size_t idx2 = ((size_t)db * NC + chunk) * (DI * DS) + (size_t)(d0 + dsub) * DS + n;
    a.hloc[idx2] = h;
    a.Pc[idx2] = P;
    __syncthreads();
}

// ---------- P4: scan pass 2; 2600 floats LDS ----------
__device__ void scan_fix_tile(const MegaArgs& a, int l, int tile, int tid, float* sm)
{
    float* sdbl = sm;
    float* sdt  = sm + 1144;
    float* sxx  = sm + 1560;
    float* sy   = sm + 1976;
    float* sw   = sm + 2392;
    float* sb2  = sm + 2584;
    int dblk = tile % 24;
    int rr = tile / 24;
    int chunk = rr % NC;
    int db = rr / NC;
    int dir = db >> 2, b = db & 3;
    int d0 = dblk * 16;
    int t0 = chunk * TCH;
    size_t dofD = (size_t)db * LSEQ * DI;
    scan_stage(a, l, d0, t0, db, dir, b, true, tid, sdbl, sdt, sxx, sw, sb2);
    int wave = tid >> 6, lane = tid & 63;
    int dsub = wave * 4 + (lane >> 4);
    int n = lane & 15;
    const float* Al = (dir ? a.A_b_log : a.A_log) + (size_t)l * DI * DS;
    float Aval = -__expf(Al[(d0 + dsub) * DS + n]);
    float Dv = a.Dp[(size_t)l * DI + d0 + dsub];
    float h = 0.f;
    size_t cbase = (size_t)db * NC * (DI * DS) + (size_t)(d0 + dsub) * DS + n;
    #pragma unroll
    for (int j = 0; j < NC - 1; j++) {
        size_t idx = cbase + (size_t)j * (DI * DS);
        float pj = a.Pc[idx], hj = a.hloc[idx];
        h = (j < chunk) ? (pj * h + hj) : h;
    }
    #pragma unroll
    for (int i = 0; i < TCH; i++) {
        float dtv = sdt[i * 16 + dsub];
        float xv  = sxx[i * 16 + dsub];
        float Bv  = sdbl[i * 44 + 12 + n];
        float Cv  = sdbl[i * 44 + 28 + n];
        h = __expf(dtv * Aval) * h + (dtv * xv) * Bv;
        float p = h * Cv;
        p += __shfl_xor(p, 1);
        p += __shfl_xor(p, 2);
        p += __shfl_xor(p, 4);
        p += __shfl_xor(p, 8);
        if (n == 0) sy[i * 16 + dsub] = p + xv * Dv;
    }
    __syncthreads();
    int len = min(t0 + TCH, LSEQ) - t0;
    for (int idx = tid; idx < len * 16; idx += 256) {
        int t = idx >> 4, d = idx & 15;
        a.yraw[dofD + (size_t)(t0 + t) * DI + d0 + d] = sy[t * 16 + d];
    }
    __syncthreads();
}

// ---------- P5: fused combine + outproj (split-K=2, atomics); 6528 floats LDS ----------
__device__ void outproj_tile(const MegaArgs& a, int l, int tile, int tid, float* sm)
{
    const float* opw_l = a.opw + (size_t)l * DM * DI;
    float* As = sm;                       // 96 x 34
    float* Ws = sm + 3264;
    int bn = (tile % 6) * 32;
    int bm = ((tile / 6) % 51) * 32;
    int kbase = (tile / (6 * 51)) * 192;
    int row8 = tid >> 3, seg = tid & 7, k0 = seg * 24;
    float av[24], wreg[24];
    int m = bm + row8;
    if (m < NTOK) {
        int b = m / LSEQ, t = m % LSEQ;
        const float* yf = a.yraw + (size_t)m * DI + kbase + k0;
        const float* yb = a.yraw + (size_t)(NTOK + b * LSEQ + (LSEQ - 1 - t)) * DI + kbase + k0;
        const float* zp = a.xz + (size_t)m * (2 * DI) + DI + kbase + k0;
        #pragma unroll
        for (int i = 0; i < 24; i++) {
            float z = zp[i];
            av[i] = (yf[i] + yb[i]) * (z / (1.f + __expf(-z)));
        }
    } else {
        #pragma unroll
        for (int i = 0; i < 24; i++) av[i] = 0.f;
    }
    {
        const float* wp = opw_l + (size_t)(bn + row8) * DI + kbase + k0;
        #pragma unroll
        for (int i = 0; i < 24; i++) wreg[i] = wp[i];
    }
    int r0 = (tid >> 4) * 2, c0 = (tid & 15) * 2;
    float acc[2][2] = {};
    #pragma unroll
    for (int st = 0; st < 2; st++) {
        if (st) __syncthreads();
        if ((seg >> 2) == st) {
            int kb = k0 - st * 96;
            #pragma unroll
            for (int i = 0; i < 24; i++) {
                As[(kb + i) * 34 + row8] = av[i];
                Ws[(kb + i) * 34 + row8] = wreg[i];
            }
        }
        __syncthreads();
        #pragma unroll 8
        for (int kk = 0; kk < 96; kk++) {
            float2 aa = *(const float2*)&As[kk * 34 + r0];
            float2 ww = *(const float2*)&Ws[kk * 34 + c0];
            acc[0][0] += aa.x * ww.x; acc[0][1] += aa.x * ww.y;
            acc[1][0] += aa.y * ww.x; acc[1][1] += aa.y * ww.y;
        }
    }
    #pragma unroll
    for (int i = 0; i < 2; i++) {
        int mm = bm + r0 + i;
        if (mm >= NTOK) continue;
        #pragma unroll
        for (int j = 0; j < 2; j++)
            atomicAdd(&a.hidden[(size_t)mm * DM + bn + c0 + j], acc[i][j]);
    }
    __syncthreads();
}

// ---------- final rmsnorm + head; 256 floats LDS ----------
__device__ void head_tile(const MegaArgs& a, int b, int tid, float* sm)
{
    float* hb = sm;                        // 192
    float* wsum = sm + 192;                // 4
    int c = tid;
    float r = 0.f, s = 0.f;
    if (c < DM) {
        int idx = (b * LSEQ) * DM + c;
        r = a.resA[idx] + a.hidden[idx];
        s = r * r;
    }
    #pragma unroll
    for (int off = 32; off > 0; off >>= 1) s += __shfl_down(s, off);
    if ((tid & 63) == 0) wsum[tid >> 6] = s;
    __syncthreads();
    float tot = wsum[0] + wsum[1] + wsum[2] + wsum[3];
    float rms = rsqrtf(tot / (float)DM + 1e-5f);
    if (c < DM) hb[c] = r * rms * a.norm_f[c];
    __syncthreads();
    if (c < NCLS) {
        float acc = a.head_b[c];
        #pragma unroll 8
        for (int k = 0; k < DM; k++) acc += hb[k] * a.head_w[c * DM + k];
        if (a.probe[0] == 0x3F80u)
            ((__hip_bfloat16*)a.out)[b * NCLS + c] = __float2bfloat16(acc);
        else
            ((float*)a.out)[b * NCLS + c] = acc;
    }
}

// ---------- cooperative megakernel (grid-stride over tiles, grid sized by host) ----------
__global__ __launch_bounds__(256, 2) void mega_k(MegaArgs a)
{
    cg::grid_group gg = cg::this_grid();
    __shared__ float sm[7776];            // 31104 B arena
    int nb = gridDim.x, gb = blockIdx.x, tid = threadIdx.x;

    for (int t = gb; t < NTOK / 4; t += nb) patch_tile(a, t, tid, sm);
    gg.sync();

    for (int l = 0; l < DEPTH; l++) {
        for (int i = gb * 256 + tid; i < 2 * NTOK * 44; i += nb * 256) a.dbl[i] = 0.f;
        for (int t = gb; t < NT1; t += nb) xz_tile(a, l, t, tid, sm);
        gg.sync();
        for (int t = gb; t < NT2; t += nb) xproj_tile(a, l, t, tid, sm);
        gg.sync();
        for (int i = gb * 256 + tid; i < NTOK * DM; i += nb * 256) a.hidden[i] = 0.f;
        for (int t = gb; t < NT3; t += nb) scan_part_tile(a, l, t, tid, sm);
        gg.sync();
        for (int t = gb; t < NT4; t += nb) scan_fix_tile(a, l, t, tid, sm);
        gg.sync();
        for (int t = gb; t < NT5; t += nb) outproj_tile(a, l, t, tid, sm);
        gg.sync();
    }
    if (gb < BATCH) head_tile(a, gb, tid, sm);
}

// ---------- fallback wrappers (same device code, one tile per block) ----------
__global__ __launch_bounds__(256) void patch_k(MegaArgs a)
{ __shared__ float sm[1024]; patch_tile(a, blockIdx.x, threadIdx.x, sm); }

__global__ __launch_bounds__(256) void p1_k(MegaArgs a, int l)
{
    __shared__ float sm[6528];
    for (int i = blockIdx.x * 256 + threadIdx.x; i < 2 * NTOK * 44; i += gridDim.x * 256)
        a.dbl[i] = 0.f;
    xz_tile(a, l, blockIdx.x, threadIdx.x, sm);
}
__global__ __launch_bounds__(256) void p2_k(MegaArgs a, int l)
{ __shared__ float sm[7776]; xproj_tile(a, l, blockIdx.x, threadIdx.x, sm); }

__global__ __launch_bounds__(256) void p3_k(MegaArgs a, int l)
{
    __shared__ float sm[2184];
    for (int i = blockIdx.x * 256 + threadIdx.x; i < NTOK * DM; i += gridDim.x * 256)
        a.hidden[i] = 0.f;
    scan_part_tile(a, l, blockIdx.x, threadIdx.x, sm);
}
__global__ __launch_bounds__(256) void p4_k(MegaArgs a, int l)
{ __shared__ float sm[2600]; scan_fix_tile(a, l, blockIdx.x, threadIdx.x, sm); }

__global__ __launch_bounds__(256) void p5_k(MegaArgs a, int l)
{ __shared__ float sm[6528]; outproj_tile(a, l, blockIdx.x, threadIdx.x, sm); }

__global__ __launch_bounds__(256) void head_k(MegaArgs a)
{ __shared__ float sm[256]; head_tile(a, blockIdx.x, threadIdx.x, sm); }

extern "C" void kernel_launch(void* const* d_in, const int* in_sizes, int n_in,
                              void* d_out, int out_size, void* d_ws, size_t ws_size,
                              hipStream_t stream)
{
    (void)in_sizes; (void)n_in; (void)out_size; (void)ws_size;
    float* ws = (float*)d_ws;
    const size_t nTokDM = (size_t)NTOK * DM;
    const size_t nTokXZ = (size_t)NTOK * 2 * DI;
    const size_t nDirDI = (size_t)2 * NTOK * DI;
    const size_t nDir44 = (size_t)2 * NTOK * 44;
    const size_t nChunk = (size_t)2 * BATCH * NC * DI * DS;

    MegaArgs a;
    a.x      = (const float*)d_in[0];
    a.pe_w   = (const float*)d_in[1];
    a.pe_b   = (const float*)d_in[2];
    a.cls    = (const float*)d_in[3];
    a.pos    = (const float*)d_in[4];
    a.norm_w = (const float*)d_in[5];
    a.ipw    = (const float*)d_in[6];
    a.cw     = (const float*)d_in[7];
    a.cb     = (const float*)d_in[8];
    a.xpw    = (const float*)d_in[9];
    a.dtw    = (const float*)d_in[10];
    a.dtb    = (const float*)d_in[11];
    a.A_log  = (const float*)d_in[12];
    a.A_b_log= (const float*)d_in[13];
    a.Dp     = (const float*)d_in[14];
    a.opw    = (const float*)d_in[15];
    a.norm_f = (const float*)d_in[16];
    a.head_w = (const float*)d_in[17];
    a.head_b = (const float*)d_in[18];
    a.probe  = (const unsigned short*)d_in[14];

    a.resA   = ws;
    a.resB   = a.resA + nTokDM;
    a.hidden = a.resB + nTokDM;
    a.xz     = a.hidden + nTokDM;
    a.dbl    = a.xz + nTokXZ;
    a.yraw   = a.dbl + nDir44;
    a.hloc   = a.yraw + nDirDI;
    a.Pc     = a.hloc + nChunk;
    a.out    = d_out;

    // Size the cooperative grid to guaranteed co-residency; verify the launch.
    int maxPerCU = 0;
    hipError_t oe = hipOccupancyMaxActiveBlocksPerMultiprocessor(&maxPerCU, mega_k, 256, 0);
    hipError_t le = hipErrorUnknown;
    if (oe == hipSuccess && maxPerCU > 0) {
        int grid = maxPerCU * 256;
        if (grid > NT1) grid = NT1;       // no phase has more than 3072 tiles; 1224 is plenty
        void* params[] = { &a };
        le = hipLaunchCooperativeKernel((void*)mega_k, dim3(grid), dim3(256),
                                        params, 0, stream);
    }
    if (le != hipSuccess) {
        (void)hipGetLastError();          // clear sticky error, use fallback path
        patch_k<<<NTOK / 4, 256, 0, stream>>>(a);
        for (int l = 0; l < DEPTH; l++) {
            p1_k<<<NT1, 256, 0, stream>>>(a, l);
            p2_k<<<NT2, 256, 0, stream>>>(a, l);
            p3_k<<<NT3, 256, 0, stream>>>(a, l);
            p4_k<<<NT4, 256, 0, stream>>>(a, l);
            p5_k<<<NT5, 256, 0, stream>>>(a, l);
        }
        head_k<<<BATCH, 256, 0, stream>>>(a);
    }
}

// Round 10
// 8665.504 us; speedup vs baseline: 1.1536x; 1.1536x over previous
//
#include <hip/hip_runtime.h>
#include <hip/hip_bf16.h>

#define DEPTH 24
#define DM 192
#define DI 384
#define DS 16
#define DR 12
#define LSEQ 401
#define BATCH 4
#define NTOK (BATCH*LSEQ)          // 1604
#define NCLS 22
#define NC 16                      // scan time-chunks
#define TCH 26                     // ceil(401/16); last chunk = 11
#define NSLOT (8*24*NC)            // scan chain slots per layer = 3072

__device__ __forceinline__ float silu_f(float x) { return x / (1.f + __expf(-x)); }

struct Args {
    const float *x, *pe_w, *pe_b, *cls, *pos, *norm_w, *ipw, *cw, *cb,
                *xpw, *dtw, *dtb, *A_log, *A_b_log, *Dp, *opw, *norm_f,
                *head_w, *head_b;
    float *resA, *resB, *hidden, *xz, *dbl, *yraw, *hinc;
    int *flags, *ticks;
    void* out;
    const unsigned short* probe;
};

// ---------- patch embed + cls + pos; also zero chain flags/tickets ----------
__global__ __launch_bounds__(256) void patch_k(Args a)
{
    __shared__ float xp[4][256];
    int tid = threadIdx.x;
    for (int i = blockIdx.x * 256 + tid; i < DEPTH * NSLOT + DEPTH; i += gridDim.x * 256) {
        if (i < DEPTH * NSLOT) a.flags[i] = 0; else a.ticks[i - DEPTH * NSLOT] = 0;
    }
    int g0 = blockIdx.x * 4;
    #pragma unroll
    for (int j = 0; j < 4; j++) {
        int g = g0 + j;
        int b = g / LSEQ, t = g % LSEQ;
        if (t != 0) {
            int p = t - 1, pi = p / 200, pj = p % 200;
            xp[j][tid] = a.x[((size_t)(b * 32 + pi * 16 + (tid >> 4))) * 3200 + pj * 16 + (tid & 15)];
        }
    }
    __syncthreads();
    int c = tid;
    if (c < DM) {
        float acc[4] = {0.f, 0.f, 0.f, 0.f};
        for (int k = 0; k < 256; k++) {
            float w = a.pe_w[c * 256 + k];
            #pragma unroll
            for (int j = 0; j < 4; j++) acc[j] += xp[j][k] * w;
        }
        #pragma unroll
        for (int j = 0; j < 4; j++) {
            int g = g0 + j;
            int t = g % LSEQ;
            float v = (t == 0) ? a.cls[c] : (acc[j] + a.pe_b[c]);
            v += a.pos[t * DM + c];
            a.resA[(size_t)g * DM + c] = v;
            a.hidden[(size_t)g * DM + c] = v;
        }
    }
}

// ---------- P1: fused prenorm + xz GEMM (32x32 tile, 2-stage K); zeroes dbl ----------
__global__ __launch_bounds__(256) void xzpre_k(Args a, int l)
{
    __shared__ float As[96][34];
    __shared__ float Ws[96][34];
    const float* rin = (l & 1) ? a.resB : a.resA;
    float* rout      = (l & 1) ? a.resA : a.resB;
    const float* nw    = a.norm_w + (size_t)l * DM;
    const float* ipw_l = a.ipw + (size_t)l * 2 * DI * DM;
    int tid = threadIdx.x;
    for (int i = (blockIdx.y * 24 + blockIdx.x) * 256 + tid; i < 2 * NTOK * 44; i += 24 * 51 * 256)
        a.dbl[i] = 0.f;                          // for xproj atomics
    int bn = blockIdx.x * 32;
    int bm = blockIdx.y * 32;
    int row8 = tid >> 3, seg = tid & 7, k0 = seg * 24;
    int m = bm + row8;
    float r[24];
    float s = 0.f;
    if (m < NTOK) {
        const float* rp = rin + (size_t)m * DM + k0;
        const float* hp = a.hidden + (size_t)m * DM + k0;
        #pragma unroll
        for (int i = 0; i < 24; i++) { r[i] = rp[i] + hp[i]; s += r[i] * r[i]; }
    } else {
        #pragma unroll
        for (int i = 0; i < 24; i++) r[i] = 0.f;
    }
    s += __shfl_down(s, 4, 8);
    s += __shfl_down(s, 2, 8);
    s += __shfl_down(s, 1, 8);
    float tot = __shfl(s, 0, 8);
    float rms = rsqrtf(tot / (float)DM + 1e-5f);
    if (bn == 0 && m < NTOK) {
        float* ro = rout + (size_t)m * DM + k0;
        #pragma unroll
        for (int i = 0; i < 24; i++) ro[i] = r[i];
    }
    float av[24], wreg[24];
    {
        const float* wp = ipw_l + (size_t)(bn + row8) * DM + k0;
        #pragma unroll
        for (int i = 0; i < 24; i++) {
            av[i] = r[i] * rms * nw[k0 + i];
            wreg[i] = wp[i];
        }
    }
    int r0 = (tid >> 4) * 2, c0 = (tid & 15) * 2;
    float acc[2][2] = {};
    #pragma unroll
    for (int st = 0; st < 2; st++) {
        if (st) __syncthreads();
        if ((seg >> 2) == st) {
            int kb = k0 - st * 96;
            #pragma unroll
            for (int i = 0; i < 24; i++) {
                As[kb + i][row8] = av[i];
                Ws[kb + i][row8] = wreg[i];
            }
        }
        __syncthreads();
        #pragma unroll 8
        for (int kk = 0; kk < 96; kk++) {
            float2 aa = *(const float2*)&As[kk][r0];
            float2 ww = *(const float2*)&Ws[kk][c0];
            acc[0][0] += aa.x * ww.x; acc[0][1] += aa.x * ww.y;
            acc[1][0] += aa.y * ww.x; acc[1][1] += aa.y * ww.y;
        }
    }
    #pragma unroll
    for (int i = 0; i < 2; i++) {
        int mm = bm + r0 + i;
        if (mm >= NTOK) continue;
        #pragma unroll
        for (int j = 0; j < 2; j++)
            a.xz[(size_t)mm * (2 * DI) + bn + c0 + j] = acc[i][j];
    }
}

// ---------- P2: xproj with conv fused (split-K=4, atomics into dbl); zeroes hidden ----------
__global__ __launch_bounds__(256) void xproj_k(Args a, int l)
{
    __shared__ float As[96][33];
    __shared__ float Ws[96][48];
    const float* cw_l  = a.cw + (size_t)l * DI * 4;
    const float* cb_l  = a.cb + (size_t)l * DI;
    const float* xpw_l = a.xpw + (size_t)l * 44 * DI;
    int tid = threadIdx.x;
    for (int i = (blockIdx.y * 4 + blockIdx.x) * 256 + tid; i < NTOK * DM; i += 4 * 101 * 256)
        a.hidden[i] = 0.f;                       // for outproj atomics
    int kbase = blockIdx.x * 96;
    int bm = blockIdx.y * 32;
    for (int idx = tid; idx < 96 * 32; idx += 256) {
        int k = idx >> 5, row = idx & 31;
        int m = bm + row;
        float v = 0.f;
        if (m < 2 * NTOK) {
            int dir = m / NTOK;
            int rr = m - dir * NTOK;
            int b = rr / LSEQ, t = rr % LSEQ;
            int ch = kbase + k;
            float acc = cb_l[ch];
            #pragma unroll
            for (int j = 0; j < 4; j++) {
                int tt = t - 3 + j;
                if (tt >= 0) {
                    int st = dir ? (LSEQ - 1 - tt) : tt;
                    acc += cw_l[ch * 4 + j] * a.xz[((size_t)(b * LSEQ + st)) * (2 * DI) + ch];
                }
            }
            v = silu_f(acc);
        }
        As[k][row] = v;
    }
    for (int i = tid; i < 96 * 48; i += 256) {
        int k = i / 48, rr = i % 48;
        Ws[k][rr] = (rr < 44) ? xpw_l[(size_t)rr * DI + kbase + k] : 0.f;
    }
    __syncthreads();
    int row = tid & 31, cg_ = tid >> 5;
    int cbase = cg_ * 6;
    float acc[6] = {};
    #pragma unroll 4
    for (int kk = 0; kk < 96; kk++) {
        float av = As[kk][row];
        #pragma unroll
        for (int j = 0; j < 6; j++) acc[j] += av * Ws[kk][cbase + j];
    }
    int m = bm + row;
    if (m < 2 * NTOK) {
        #pragma unroll
        for (int j = 0; j < 6; j++) {
            int cc = cbase + j;
            if (cc < 44) atomicAdd(&a.dbl[(size_t)m * 44 + cc], acc[j]);
        }
    }
}

// ---------- P3: single-pass chained scan (ticket-ordered, decoupled chaining) ----------
// 3072 blocks; virtual id via ticket => chunk-major order, deadlock-free.
__global__ __launch_bounds__(256) void scan_k(Args a, int l)
{
    __shared__ float sdbl[TCH][44];
    __shared__ float sdt[TCH][16];
    __shared__ float sxx[TCH][16];
    __shared__ float sy[TCH][16];
    __shared__ float sw[16][12];
    __shared__ float sb2[16];
    __shared__ int s_vb;
    int tid = threadIdx.x;
    if (tid == 0) s_vb = atomicAdd(&a.ticks[l], 1);
    __syncthreads();
    int vb = s_vb;
    int chunk = vb / 192;                 // slowest-varying => chunk 0 tickets first
    int rem = vb - chunk * 192;
    int db = rem / 24, dblk = rem - (rem / 24) * 24;
    int dir = db >> 2, b = db & 3;
    int d0 = dblk * 16;
    int t0 = chunk * TCH;
    bool guard = (chunk == NC - 1);
    const float* cw_l  = a.cw + (size_t)l * DI * 4;
    const float* cb_l  = a.cb + (size_t)l * DI;
    const float* dtw_l = a.dtw + (size_t)l * DI * DR;
    const float* dtb_l = a.dtb + (size_t)l * DI;
    size_t dofD = (size_t)db * LSEQ * DI;
    size_t dof44 = (size_t)db * LSEQ * 44;
    // stage dbl slab, conv+silu xx, dt
    for (int i = tid; i < TCH * 44; i += 256) {
        int t = i / 44, cc = i - t * 44;
        bool v = !guard || (t0 + t) < LSEQ;
        sdbl[t][cc] = v ? a.dbl[dof44 + (size_t)(t0 + t) * 44 + cc] : 0.f;
    }
    if (tid < 192) { int d = tid / 12, r = tid - d * 12; sw[d][r] = dtw_l[(size_t)(d0 + d) * 12 + r]; }
    if (tid < 16) sb2[tid] = dtb_l[d0 + tid];
    for (int i = tid; i < TCH * 16; i += 256) {
        int t = i >> 4, d = i & 15;
        int tq = t0 + t, ch = d0 + d;
        float v = 0.f;
        if (!guard || tq < LSEQ) {
            float acc = cb_l[ch];
            #pragma unroll
            for (int j = 0; j < 4; j++) {
                int tt = tq - 3 + j;
                if (tt >= 0) {
                    int st = dir ? (LSEQ - 1 - tt) : tt;
                    acc += cw_l[ch * 4 + j] * a.xz[((size_t)(b * LSEQ + st)) * (2 * DI) + ch];
                }
            }
            v = silu_f(acc);
        }
        sxx[t][d] = v;
    }
    __syncthreads();
    for (int i = tid; i < TCH * 16; i += 256) {
        int t = i >> 4, d = i & 15;
        float a2 = sb2[d];
        #pragma unroll
        for (int r = 0; r < 12; r++) a2 += sdbl[t][r] * sw[d][r];
        sdt[t][d] = (a2 > 15.f) ? a2 : __logf(1.f + __expf(a2));
    }
    __syncthreads();
    int wave = tid >> 6, lane = tid & 63;
    int dsub = wave * 4 + (lane >> 4);
    int n = lane & 15;
    const float* Al = (dir ? a.A_b_log : a.A_log) + (size_t)l * DI * DS;
    float Aval = -__expf(Al[(d0 + dsub) * DS + n]);
    float Dv = a.Dp[(size_t)l * DI + d0 + dsub];
    // local scan: padded steps are identity (dt=0 -> dA=1, add 0)
    float h = 0.f, P = 1.f;
    #pragma unroll
    for (int i = 0; i < TCH; i++) {
        float dtv = sdt[i][dsub];
        float dA = __expf(dtv * Aval);
        h = dA * h + (dtv * sxx[i][dsub]) * sdbl[i][12 + n];
        P *= dA;
    }
    // chain: wait for predecessor's inclusive state, publish ours
    int slot = (db * 24 + dblk) * NC + chunk;           // within-layer slot
    int* flg = a.flags + (size_t)l * NSLOT;
    float* hincl = a.hinc;
    float hprev = 0.f;
    if (chunk > 0) {
        if (tid == 0) {
            while (__hip_atomic_load(&flg[slot - 1], __ATOMIC_ACQUIRE,
                                     __HIP_MEMORY_SCOPE_AGENT) == 0)
                __builtin_amdgcn_s_sleep(1);
        }
        __syncthreads();
        hprev = __hip_atomic_load(&hincl[(size_t)(slot - 1) * 256 + tid],
                                  __ATOMIC_RELAXED, __HIP_MEMORY_SCOPE_AGENT);
    }
    float hme = P * hprev + h;
    __hip_atomic_store(&hincl[(size_t)slot * 256 + tid], hme,
                       __ATOMIC_RELAXED, __HIP_MEMORY_SCOPE_AGENT);
    __syncthreads();                       // all publishes done (waitcnt before barrier)
    if (tid == 0)
        __hip_atomic_store(&flg[slot], 1, __ATOMIC_RELEASE, __HIP_MEMORY_SCOPE_AGENT);
    // emit pass from h_init = hprev
    h = hprev;
    #pragma unroll
    for (int i = 0; i < TCH; i++) {
        float dtv = sdt[i][dsub];
        float xv  = sxx[i][dsub];
        h = __expf(dtv * Aval) * h + (dtv * xv) * sdbl[i][12 + n];
        float p = h * sdbl[i][28 + n];
        p += __shfl_xor(p, 1);
        p += __shfl_xor(p, 2);
        p += __shfl_xor(p, 4);
        p += __shfl_xor(p, 8);
        if (n == 0) sy[i][dsub] = p + xv * Dv;
    }
    __syncthreads();
    int len = min(t0 + TCH, LSEQ) - t0;
    for (int idx = tid; idx < len * 16; idx += 256) {
        int t = idx >> 4, d = idx & 15;
        a.yraw[dofD + (size_t)(t0 + t) * DI + d0 + d] = sy[t][d];
    }
}

// ---------- P4: fused combine + outproj (split-K=2, atomics into hidden) ----------
__global__ __launch_bounds__(256) void outproj_k(Args a, int l)
{
    __shared__ float As[96][34];
    __shared__ float Ws[96][34];
    const float* opw_l = a.opw + (size_t)l * DM * DI;
    int tid = threadIdx.x;
    int bn = blockIdx.x * 32;
    int bm = blockIdx.y * 32;
    int kbase = blockIdx.z * 192;
    int row8 = tid >> 3, seg = tid & 7, k0 = seg * 24;
    float av[24], wreg[24];
    int m = bm + row8;
    if (m < NTOK) {
        int b = m / LSEQ, t = m % LSEQ;
        const float* yf = a.yraw + (size_t)m * DI + kbase + k0;
        const float* yb = a.yraw + (size_t)(NTOK + b * LSEQ + (LSEQ - 1 - t)) * DI + kbase + k0;
        const float* zp = a.xz + (size_t)m * (2 * DI) + DI + kbase + k0;
        #pragma unroll
        for (int i = 0; i < 24; i++) {
            float z = zp[i];
            av[i] = (yf[i] + yb[i]) * (z / (1.f + __expf(-z)));
        }
    } else {
        #pragma unroll
        for (int i = 0; i < 24; i++) av[i] = 0.f;
    }
    {
        const float* wp = opw_l + (size_t)(bn + row8) * DI + kbase + k0;
        #pragma unroll
        for (int i = 0; i < 24; i++) wreg[i] = wp[i];
    }
    int r0 = (tid >> 4) * 2, c0 = (tid & 15) * 2;
    float acc[2][2] = {};
    #pragma unroll
    for (int st = 0; st < 2; st++) {
        if (st) __syncthreads();
        if ((seg >> 2) == st) {
            int kb = k0 - st * 96;
            #pragma unroll
            for (int i = 0; i < 24; i++) {
                As[kb + i][row8] = av[i];
                Ws[kb + i][row8] = wreg[i];
            }
        }
        __syncthreads();
        #pragma unroll 8
        for (int kk = 0; kk < 96; kk++) {
            float2 aa = *(const float2*)&As[kk][r0];
            float2 ww = *(const float2*)&Ws[kk][c0];
            acc[0][0] += aa.x * ww.x; acc[0][1] += aa.x * ww.y;
            acc[1][0] += aa.y * ww.x; acc[1][1] += aa.y * ww.y;
        }
    }
    #pragma unroll
    for (int i = 0; i < 2; i++) {
        int mm = bm + r0 + i;
        if (mm >= NTOK) continue;
        #pragma unroll
        for (int j = 0; j < 2; j++)
            atomicAdd(&a.hidden[(size_t)mm * DM + bn + c0 + j], acc[i][j]);
    }
}

// ---------- final rmsnorm on token 0 + head ----------
__global__ __launch_bounds__(256) void head_k(Args a)
{
    __shared__ float hb[DM];
    __shared__ float wsum[4];
    int b = blockIdx.x, tid = threadIdx.x, c = tid;
    float r = 0.f, s = 0.f;
    if (c < DM) {
        int idx = (b * LSEQ) * DM + c;
        r = a.resA[idx] + a.hidden[idx];
        s = r * r;
    }
    #pragma unroll
    for (int off = 32; off > 0; off >>= 1) s += __shfl_down(s, off);
    if ((tid & 63) == 0) wsum[tid >> 6] = s;
    __syncthreads();
    float tot = wsum[0] + wsum[1] + wsum[2] + wsum[3];
    float rms = rsqrtf(tot / (float)DM + 1e-5f);
    if (c < DM) hb[c] = r * rms * a.norm_f[c];
    __syncthreads();
    if (c < NCLS) {
        float acc = a.head_b[c];
        #pragma unroll 8
        for (int k = 0; k < DM; k++) acc += hb[k] * a.head_w[c * DM + k];
        if (a.probe[0] == 0x3F80u)
            ((__hip_bfloat16*)a.out)[b * NCLS + c] = __float2bfloat16(acc);
        else
            ((float*)a.out)[b * NCLS + c] = acc;
    }
}

extern "C" void kernel_launch(void* const* d_in, const int* in_sizes, int n_in,
                              void* d_out, int out_size, void* d_ws, size_t ws_size,
                              hipStream_t stream)
{
    (void)in_sizes; (void)n_in; (void)out_size; (void)ws_size;
    float* ws = (float*)d_ws;
    const size_t nTokDM = (size_t)NTOK * DM;
    const size_t nTokXZ = (size_t)NTOK * 2 * DI;
    const size_t nDirDI = (size_t)2 * NTOK * DI;
    const size_t nDir44 = (size_t)2 * NTOK * 44;

    Args a;
    a.x      = (const float*)d_in[0];
    a.pe_w   = (const float*)d_in[1];
    a.pe_b   = (const float*)d_in[2];
    a.cls    = (const float*)d_in[3];
    a.pos    = (const float*)d_in[4];
    a.norm_w = (const float*)d_in[5];
    a.ipw    = (const float*)d_in[6];
    a.cw     = (const float*)d_in[7];
    a.cb     = (const float*)d_in[8];
    a.xpw    = (const float*)d_in[9];
    a.dtw    = (const float*)d_in[10];
    a.dtb    = (const float*)d_in[11];
    a.A_log  = (const float*)d_in[12];
    a.A_b_log= (const float*)d_in[13];
    a.Dp     = (const float*)d_in[14];
    a.opw    = (const float*)d_in[15];
    a.norm_f = (const float*)d_in[16];
    a.head_w = (const float*)d_in[17];
    a.head_b = (const float*)d_in[18];
    a.probe  = (const unsigned short*)d_in[14];

    a.resA   = ws;
    a.resB   = a.resA + nTokDM;
    a.hidden = a.resB + nTokDM;
    a.xz     = a.hidden + nTokDM;
    a.dbl    = a.xz + nTokXZ;
    a.yraw   = a.dbl + nDir44;
    a.hinc   = a.yraw + nDirDI;                       // NSLOT*256 floats
    a.flags  = (int*)(a.hinc + (size_t)NSLOT * 256);  // DEPTH*NSLOT ints
    a.ticks  = a.flags + DEPTH * NSLOT;               // DEPTH ints
    a.out    = d_out;

    patch_k<<<NTOK / 4, 256, 0, stream>>>(a);
    for (int l = 0; l < DEPTH; l++) {
        xzpre_k<<<dim3(24, 51), 256, 0, stream>>>(a, l);
        xproj_k<<<dim3(4, 101), 256, 0, stream>>>(a, l);
        scan_k<<<NSLOT, 256, 0, stream>>>(a, l);
        outproj_k<<<dim3(6, 51, 2), 256, 0, stream>>>(a, l);
    }
    head_k<<<BATCH, 256, 0, stream>>>(a);
}

// Round 11
// 3194.883 us; speedup vs baseline: 3.1290x; 2.7123x over previous
//
#include <hip/hip_runtime.h>
#include <hip/hip_bf16.h>

#define DEPTH 24
#define DM 192
#define DI 384
#define DS 16
#define DR 12
#define LSEQ 401
#define BATCH 4
#define NTOK (BATCH*LSEQ)          // 1604
#define NCLS 22
#define NC 16                      // scan time-chunks
#define TCH 26                     // ceil(401/16); last chunk = 11

__device__ __forceinline__ float silu_f(float x) { return x / (1.f + __expf(-x)); }

struct Args {
    const float *x, *pe_w, *pe_b, *cls, *pos, *norm_w, *ipw, *cw, *cb,
                *xpw, *dtw, *dtb, *A_log, *A_b_log, *Dp, *opw, *norm_f,
                *head_w, *head_b;
    float *resA, *resB, *hidden, *xz, *dbl, *yraw, *hloc, *Pc;
    void* out;
    const unsigned short* probe;
};

// ---------- patch embed + cls + pos (4 tokens/block) ----------
__global__ __launch_bounds__(256) void patch_k(Args a)
{
    __shared__ float xp[4][256];
    int tid = threadIdx.x;
    int g0 = blockIdx.x * 4;
    #pragma unroll
    for (int j = 0; j < 4; j++) {
        int g = g0 + j;
        int b = g / LSEQ, t = g % LSEQ;
        if (t != 0) {
            int p = t - 1, pi = p / 200, pj = p % 200;
            xp[j][tid] = a.x[((size_t)(b * 32 + pi * 16 + (tid >> 4))) * 3200 + pj * 16 + (tid & 15)];
        }
    }
    __syncthreads();
    int c = tid;
    if (c < DM) {
        float acc[4] = {0.f, 0.f, 0.f, 0.f};
        for (int k = 0; k < 256; k++) {
            float w = a.pe_w[c * 256 + k];
            #pragma unroll
            for (int j = 0; j < 4; j++) acc[j] += xp[j][k] * w;
        }
        #pragma unroll
        for (int j = 0; j < 4; j++) {
            int g = g0 + j;
            int t = g % LSEQ;
            float v = (t == 0) ? a.cls[c] : (acc[j] + a.pe_b[c]);
            v += a.pos[t * DM + c];
            a.resA[(size_t)g * DM + c] = v;
            a.hidden[(size_t)g * DM + c] = v;
        }
    }
}

// ---------- P1: fused prenorm + xz GEMM (32x32 tile, 2-stage K); zeroes dbl ----------
__global__ __launch_bounds__(256) void xzpre_k(Args a, int l)
{
    __shared__ float As[96][34];
    __shared__ float Ws[96][34];
    const float* rin = (l & 1) ? a.resB : a.resA;
    float* rout      = (l & 1) ? a.resA : a.resB;
    const float* nw    = a.norm_w + (size_t)l * DM;
    const float* ipw_l = a.ipw + (size_t)l * 2 * DI * DM;
    int tid = threadIdx.x;
    for (int i = (blockIdx.y * 24 + blockIdx.x) * 256 + tid; i < 2 * NTOK * 44; i += 24 * 51 * 256)
        a.dbl[i] = 0.f;                          // for xproj atomics
    int bn = blockIdx.x * 32;
    int bm = blockIdx.y * 32;
    int row8 = tid >> 3, seg = tid & 7, k0 = seg * 24;
    int m = bm + row8;
    float r[24];
    float s = 0.f;
    if (m < NTOK) {
        const float* rp = rin + (size_t)m * DM + k0;
        const float* hp = a.hidden + (size_t)m * DM + k0;
        #pragma unroll
        for (int i = 0; i < 24; i++) { r[i] = rp[i] + hp[i]; s += r[i] * r[i]; }
    } else {
        #pragma unroll
        for (int i = 0; i < 24; i++) r[i] = 0.f;
    }
    s += __shfl_down(s, 4, 8);
    s += __shfl_down(s, 2, 8);
    s += __shfl_down(s, 1, 8);
    float tot = __shfl(s, 0, 8);
    float rms = rsqrtf(tot / (float)DM + 1e-5f);
    if (bn == 0 && m < NTOK) {
        float* ro = rout + (size_t)m * DM + k0;
        #pragma unroll
        for (int i = 0; i < 24; i++) ro[i] = r[i];
    }
    float av[24], wreg[24];
    {
        const float* wp = ipw_l + (size_t)(bn + row8) * DM + k0;
        #pragma unroll
        for (int i = 0; i < 24; i++) {
            av[i] = r[i] * rms * nw[k0 + i];
            wreg[i] = wp[i];
        }
    }
    int r0 = (tid >> 4) * 2, c0 = (tid & 15) * 2;
    float acc[2][2] = {};
    #pragma unroll
    for (int st = 0; st < 2; st++) {
        if (st) __syncthreads();
        if ((seg >> 2) == st) {
            int kb = k0 - st * 96;
            #pragma unroll
            for (int i = 0; i < 24; i++) {
                As[kb + i][row8] = av[i];
                Ws[kb + i][row8] = wreg[i];
            }
        }
        __syncthreads();
        #pragma unroll 8
        for (int kk = 0; kk < 96; kk++) {
            float2 aa = *(const float2*)&As[kk][r0];
            float2 ww = *(const float2*)&Ws[kk][c0];
            acc[0][0] += aa.x * ww.x; acc[0][1] += aa.x * ww.y;
            acc[1][0] += aa.y * ww.x; acc[1][1] += aa.y * ww.y;
        }
    }
    #pragma unroll
    for (int i = 0; i < 2; i++) {
        int mm = bm + r0 + i;
        if (mm >= NTOK) continue;
        #pragma unroll
        for (int j = 0; j < 2; j++)
            a.xz[(size_t)mm * (2 * DI) + bn + c0 + j] = acc[i][j];
    }
}

// ---------- P2: xproj with conv fused (split-K=4, atomics into dbl); zeroes hidden ----------
__global__ __launch_bounds__(256) void xproj_k(Args a, int l)
{
    __shared__ float As[96][33];
    __shared__ float Ws[96][48];
    const float* cw_l  = a.cw + (size_t)l * DI * 4;
    const float* cb_l  = a.cb + (size_t)l * DI;
    const float* xpw_l = a.xpw + (size_t)l * 44 * DI;
    int tid = threadIdx.x;
    for (int i = (blockIdx.y * 4 + blockIdx.x) * 256 + tid; i < NTOK * DM; i += 4 * 101 * 256)
        a.hidden[i] = 0.f;                       // for outproj atomics
    int kbase = blockIdx.x * 96;
    int bm = blockIdx.y * 32;
    for (int idx = tid; idx < 96 * 32; idx += 256) {
        int k = idx >> 5, row = idx & 31;
        int m = bm + row;
        float v = 0.f;
        if (m < 2 * NTOK) {
            int dir = m / NTOK;
            int rr = m - dir * NTOK;
            int b = rr / LSEQ, t = rr % LSEQ;
            int ch = kbase + k;
            float acc = cb_l[ch];
            #pragma unroll
            for (int j = 0; j < 4; j++) {
                int tt = t - 3 + j;
                if (tt >= 0) {
                    int st = dir ? (LSEQ - 1 - tt) : tt;
                    acc += cw_l[ch * 4 + j] * a.xz[((size_t)(b * LSEQ + st)) * (2 * DI) + ch];
                }
            }
            v = silu_f(acc);
        }
        As[k][row] = v;
    }
    for (int i = tid; i < 96 * 48; i += 256) {
        int k = i / 48, rr = i % 48;
        Ws[k][rr] = (rr < 44) ? xpw_l[(size_t)rr * DI + kbase + k] : 0.f;
    }
    __syncthreads();
    int row = tid & 31, cg_ = tid >> 5;
    int cbase = cg_ * 6;
    float acc[6] = {};
    #pragma unroll 4
    for (int kk = 0; kk < 96; kk++) {
        float av = As[kk][row];
        #pragma unroll
        for (int j = 0; j < 6; j++) acc[j] += av * Ws[kk][cbase + j];
    }
    int m = bm + row;
    if (m < 2 * NTOK) {
        #pragma unroll
        for (int j = 0; j < 6; j++) {
            int cc = cbase + j;
            if (cc < 44) atomicAdd(&a.dbl[(size_t)m * 44 + cc], acc[j]);
        }
    }
}

// ---------- shared scan staging: dbl slab, conv+silu xx, dt ----------
__device__ void scan_stage(const Args& a, int l, int d0, int t0, int db,
                           int dir, int b, bool guard, int tid,
                           float (*sdbl)[44], float (*sdt)[16], float (*sxx)[16],
                           float (*sw)[12], float* sb2)
{
    const float* cw_l  = a.cw + (size_t)l * DI * 4;
    const float* cb_l  = a.cb + (size_t)l * DI;
    const float* dtw_l = a.dtw + (size_t)l * DI * DR;
    const float* dtb_l = a.dtb + (size_t)l * DI;
    size_t dof44 = (size_t)db * LSEQ * 44;
    for (int i = tid; i < TCH * 44; i += 256) {
        int t = i / 44, cc = i - t * 44;
        bool v = !guard || (t0 + t) < LSEQ;
        sdbl[t][cc] = v ? a.dbl[dof44 + (size_t)(t0 + t) * 44 + cc] : 0.f;
    }
    if (tid < 192) { int d = tid / 12, r = tid - d * 12; sw[d][r] = dtw_l[(size_t)(d0 + d) * 12 + r]; }
    if (tid < 16) sb2[tid] = dtb_l[d0 + tid];
    for (int i = tid; i < TCH * 16; i += 256) {
        int t = i >> 4, d = i & 15;
        int tq = t0 + t, ch = d0 + d;
        float v = 0.f;
        if (!guard || tq < LSEQ) {
            float acc = cb_l[ch];
            #pragma unroll
            for (int j = 0; j < 4; j++) {
                int tt = tq - 3 + j;
                if (tt >= 0) {
                    int st = dir ? (LSEQ - 1 - tt) : tt;
                    acc += cw_l[ch * 4 + j] * a.xz[((size_t)(b * LSEQ + st)) * (2 * DI) + ch];
                }
            }
            v = silu_f(acc);
        }
        sxx[t][d] = v;
    }
    __syncthreads();
    for (int i = tid; i < TCH * 16; i += 256) {
        int t = i >> 4, d = i & 15;
        float a2 = sb2[d];
        #pragma unroll
        for (int r = 0; r < 12; r++) a2 += sdbl[t][r] * sw[d][r];
        sdt[t][d] = (a2 > 15.f) ? a2 : __logf(1.f + __expf(a2));
    }
    __syncthreads();
}

// ---------- P3: scan pass 1 (local scan + chunk product), grid (24, NC-1, 8) ----------
__global__ __launch_bounds__(256) void scan_part_k(Args a, int l)
{
    __shared__ float sdbl[TCH][44];
    __shared__ float sdt[TCH][16];
    __shared__ float sxx[TCH][16];
    __shared__ float sw[16][12];
    __shared__ float sb2[16];
    int dblk = blockIdx.x, chunk = blockIdx.y;
    int db = blockIdx.z;
    int dir = db >> 2, b = db & 3;
    int tid = threadIdx.x;
    int d0 = dblk * 16;
    int t0 = chunk * TCH;
    scan_stage(a, l, d0, t0, db, dir, b, false, tid, sdbl, sdt, sxx, sw, sb2);
    int wave = tid >> 6, lane = tid & 63;
    int dsub = wave * 4 + (lane >> 4);
    int n = lane & 15;
    const float* Al = (dir ? a.A_b_log : a.A_log) + (size_t)l * DI * DS;
    float Aval = -__expf(Al[(d0 + dsub) * DS + n]);
    float h = 0.f, P = 1.f;
    #pragma unroll
    for (int i = 0; i < TCH; i++) {
        float dtv = sdt[i][dsub];
        float dA = __expf(dtv * Aval);
        h = dA * h + (dtv * sxx[i][dsub]) * sdbl[i][12 + n];
        P *= dA;
    }
    size_t idx2 = ((size_t)db * NC + chunk) * (DI * DS) + (size_t)(d0 + dsub) * DS + n;
    a.hloc[idx2] = h;
    a.Pc[idx2] = P;
}

// ---------- P4: scan pass 2 (compose h_init, rescan, emit y), grid (24, NC, 8) ----------
__global__ __launch_bounds__(256) void scan_fix_k(Args a, int l)
{
    __shared__ float sdbl[TCH][44];
    __shared__ float sdt[TCH][16];
    __shared__ float sxx[TCH][16];
    __shared__ float sy[TCH][16];
    __shared__ float sw[16][12];
    __shared__ float sb2[16];
    int dblk = blockIdx.x, chunk = blockIdx.y;
    int db = blockIdx.z;
    int dir = db >> 2, b = db & 3;
    int tid = threadIdx.x;
    int d0 = dblk * 16;
    int t0 = chunk * TCH;
    size_t dofD = (size_t)db * LSEQ * DI;
    scan_stage(a, l, d0, t0, db, dir, b, true, tid, sdbl, sdt, sxx, sw, sb2);
    int wave = tid >> 6, lane = tid & 63;
    int dsub = wave * 4 + (lane >> 4);
    int n = lane & 15;
    const float* Al = (dir ? a.A_b_log : a.A_log) + (size_t)l * DI * DS;
    float Aval = -__expf(Al[(d0 + dsub) * DS + n]);
    float Dv = a.Dp[(size_t)l * DI + d0 + dsub];
    float h = 0.f;
    size_t cbase = (size_t)db * NC * (DI * DS) + (size_t)(d0 + dsub) * DS + n;
    #pragma unroll
    for (int j = 0; j < NC - 1; j++) {
        size_t idx = cbase + (size_t)j * (DI * DS);
        float pj = a.Pc[idx], hj = a.hloc[idx];
        h = (j < chunk) ? (pj * h + hj) : h;
    }
    #pragma unroll
    for (int i = 0; i < TCH; i++) {
        float dtv = sdt[i][dsub];
        float xv  = sxx[i][dsub];
        h = __expf(dtv * Aval) * h + (dtv * xv) * sdbl[i][12 + n];
        float p = h * sdbl[i][28 + n];
        p += __shfl_xor(p, 1);
        p += __shfl_xor(p, 2);
        p += __shfl_xor(p, 4);
        p += __shfl_xor(p, 8);
        if (n == 0) sy[i][dsub] = p + xv * Dv;
    }
    __syncthreads();
    int len = min(t0 + TCH, LSEQ) - t0;
    for (int idx = tid; idx < len * 16; idx += 256) {
        int t = idx >> 4, d = idx & 15;
        a.yraw[dofD + (size_t)(t0 + t) * DI + d0 + d] = sy[t][d];
    }
}

// ---------- P5: fused combine + outproj (split-K=2, atomics into hidden) ----------
__global__ __launch_bounds__(256) void outproj_k(Args a, int l)
{
    __shared__ float As[96][34];
    __shared__ float Ws[96][34];
    const float* opw_l = a.opw + (size_t)l * DM * DI;
    int tid = threadIdx.x;
    int bn = blockIdx.x * 32;
    int bm = blockIdx.y * 32;
    int kbase = blockIdx.z * 192;
    int row8 = tid >> 3, seg = tid & 7, k0 = seg * 24;
    float av[24], wreg[24];
    int m = bm + row8;
    if (m < NTOK) {
        int b = m / LSEQ, t = m % LSEQ;
        const float* yf = a.yraw + (size_t)m * DI + kbase + k0;
        const float* yb = a.yraw + (size_t)(NTOK + b * LSEQ + (LSEQ - 1 - t)) * DI + kbase + k0;
        const float* zp = a.xz + (size_t)m * (2 * DI) + DI + kbase + k0;
        #pragma unroll
        for (int i = 0; i < 24; i++) {
            float z = zp[i];
            av[i] = (yf[i] + yb[i]) * (z / (1.f + __expf(-z)));
        }
    } else {
        #pragma unroll
        for (int i = 0; i < 24; i++) av[i] = 0.f;
    }
    {
        const float* wp = opw_l + (size_t)(bn + row8) * DI + kbase + k0;
        #pragma unroll
        for (int i = 0; i < 24; i++) wreg[i] = wp[i];
    }
    int r0 = (tid >> 4) * 2, c0 = (tid & 15) * 2;
    float acc[2][2] = {};
    #pragma unroll
    for (int st = 0; st < 2; st++) {
        if (st) __syncthreads();
        if ((seg >> 2) == st) {
            int kb = k0 - st * 96;
            #pragma unroll
            for (int i = 0; i < 24; i++) {
                As[kb + i][row8] = av[i];
                Ws[kb + i][row8] = wreg[i];
            }
        }
        __syncthreads();
        #pragma unroll 8
        for (int kk = 0; kk < 96; kk++) {
            float2 aa = *(const float2*)&As[kk][r0];
            float2 ww = *(const float2*)&Ws[kk][c0];
            acc[0][0] += aa.x * ww.x; acc[0][1] += aa.x * ww.y;
            acc[1][0] += aa.y * ww.x; acc[1][1] += aa.y * ww.y;
        }
    }
    #pragma unroll
    for (int i = 0; i < 2; i++) {
        int mm = bm + r0 + i;
        if (mm >= NTOK) continue;
        #pragma unroll
        for (int j = 0; j < 2; j++)
            atomicAdd(&a.hidden[(size_t)mm * DM + bn + c0 + j], acc[i][j]);
    }
}

// ---------- final rmsnorm on token 0 + head ----------
__global__ __launch_bounds__(256) void head_k(Args a)
{
    __shared__ float hb[DM];
    __shared__ float wsum[4];
    int b = blockIdx.x, tid = threadIdx.x, c = tid;
    float r = 0.f, s = 0.f;
    if (c < DM) {
        int idx = (b * LSEQ) * DM + c;
        r = a.resA[idx] + a.hidden[idx];
        s = r * r;
    }
    #pragma unroll
    for (int off = 32; off > 0; off >>= 1) s += __shfl_down(s, off);
    if ((tid & 63) == 0) wsum[tid >> 6] = s;
    __syncthreads();
    float tot = wsum[0] + wsum[1] + wsum[2] + wsum[3];
    float rms = rsqrtf(tot / (float)DM + 1e-5f);
    if (c < DM) hb[c] = r * rms * a.norm_f[c];
    __syncthreads();
    if (c < NCLS) {
        float acc = a.head_b[c];
        #pragma unroll 8
        for (int k = 0; k < DM; k++) acc += hb[k] * a.head_w[c * DM + k];
        if (a.probe[0] == 0x3F80u)
            ((__hip_bfloat16*)a.out)[b * NCLS + c] = __float2bfloat16(acc);
        else
            ((float*)a.out)[b * NCLS + c] = acc;
    }
}

extern "C" void kernel_launch(void* const* d_in, const int* in_sizes, int n_in,
                              void* d_out, int out_size, void* d_ws, size_t ws_size,
                              hipStream_t stream)
{
    (void)in_sizes; (void)n_in; (void)out_size; (void)ws_size;
    float* ws = (float*)d_ws;
    const size_t nTokDM = (size_t)NTOK * DM;
    const size_t nTokXZ = (size_t)NTOK * 2 * DI;
    const size_t nDirDI = (size_t)2 * NTOK * DI;
    const size_t nDir44 = (size_t)2 * NTOK * 44;
    const size_t nChunk = (size_t)2 * BATCH * NC * DI * DS;  // 786432

    Args a;
    a.x      = (const float*)d_in[0];
    a.pe_w   = (const float*)d_in[1];
    a.pe_b   = (const float*)d_in[2];
    a.cls    = (const float*)d_in[3];
    a.pos    = (const float*)d_in[4];
    a.norm_w = (const float*)d_in[5];
    a.ipw    = (const float*)d_in[6];
    a.cw     = (const float*)d_in[7];
    a.cb     = (const float*)d_in[8];
    a.xpw    = (const float*)d_in[9];
    a.dtw    = (const float*)d_in[10];
    a.dtb    = (const float*)d_in[11];
    a.A_log  = (const float*)d_in[12];
    a.A_b_log= (const float*)d_in[13];
    a.Dp     = (const float*)d_in[14];
    a.opw    = (const float*)d_in[15];
    a.norm_f = (const float*)d_in[16];
    a.head_w = (const float*)d_in[17];
    a.head_b = (const float*)d_in[18];
    a.probe  = (const unsigned short*)d_in[14];

    a.resA   = ws;
    a.resB   = a.resA + nTokDM;
    a.hidden = a.resB + nTokDM;
    a.xz     = a.hidden + nTokDM;
    a.dbl    = a.xz + nTokXZ;
    a.yraw   = a.dbl + nDir44;
    a.hloc   = a.yraw + nDirDI;
    a.Pc     = a.hloc + nChunk;
    a.out    = d_out;

    patch_k<<<NTOK / 4, 256, 0, stream>>>(a);
    for (int l = 0; l < DEPTH; l++) {
        xzpre_k<<<dim3(24, 51), 256, 0, stream>>>(a, l);
        xproj_k<<<dim3(4, 101), 256, 0, stream>>>(a, l);
        scan_part_k<<<dim3(24, NC - 1, 8), 256, 0, stream>>>(a, l);
        scan_fix_k<<<dim3(24, NC, 8), 256, 0, stream>>>(a, l);
        outproj_k<<<dim3(6, 51, 2), 256, 0, stream>>>(a, l);
    }
    head_k<<<BATCH, 256, 0, stream>>>(a);
}